// Round 4
// baseline (727.803 us; speedup 1.0000x reference)
//
#include <hip/hip_runtime.h>

// GATv2 2-layer encoder. R4: fused Wl|Wr GEMM (N=512, BM=64 BN=256, split-bf16
// MFMA hh+hl+lh); gat_edge 4 nodes/wave with hoisted edge-weight constants.
// N=50000, E=800000, IN=256, H=4, C=64, LAT=32, ED=3.

#define NN  50000
#define EE  800000
#define HC  256     // H*C
#define NSLOPE 0.2f

typedef float f32x4 __attribute__((ext_vector_type(4)));
typedef short bf16x8 __attribute__((ext_vector_type(8)));

__device__ __forceinline__ unsigned short f2b(float f) {   // fp32 -> bf16 RNE
    unsigned u = __float_as_uint(f);
    u += 0x7FFFu + ((u >> 16) & 1u);
    return (unsigned short)(u >> 16);
}
__device__ __forceinline__ float b2f(unsigned short h) {
    return __uint_as_float((unsigned)h << 16);
}

// ---------------- CSR build ----------------
__global__ __launch_bounds__(256) void deg_kernel(
    const int* __restrict__ dst, int* __restrict__ deg)
{
    int i = blockIdx.x * 256 + threadIdx.x;      // one int4 (4 edges) per thread
    if (i >= EE / 4) return;
    int4 v = ((const int4*)dst)[i];
    atomicAdd(&deg[v.x], 1);
    atomicAdd(&deg[v.y], 1);
    atomicAdd(&deg[v.z], 1);
    atomicAdd(&deg[v.w], 1);
}

__global__ __launch_bounds__(1024) void scan_kernel(
    const int* __restrict__ deg, int* __restrict__ row_start, int* __restrict__ cursor)
{
    __shared__ int sums[1024];
    const int tid = threadIdx.x;
    const int CH = (NN + 1023) / 1024;           // 49
    int b = tid * CH, e = min(b + CH, NN);
    int s = 0;
    for (int i = b; i < e; i++) s += deg[i];
    sums[tid] = s;
    __syncthreads();
    for (int off = 1; off < 1024; off <<= 1) {
        int v = (tid >= off) ? sums[tid - off] : 0;
        __syncthreads();
        sums[tid] += v;
        __syncthreads();
    }
    int run = (tid == 0) ? 0 : sums[tid - 1];
    for (int i = b; i < e; i++) {
        row_start[i] = run;
        cursor[i]    = run;
        run += deg[i];
    }
    if (tid == 0) row_start[NN] = EE;
}

__global__ __launch_bounds__(256) void scatter_kernel(
    const int* __restrict__ ei, const float* __restrict__ ea,
    int* __restrict__ cursor, float4* __restrict__ csr)
{
    int i = blockIdx.x * 256 + threadIdx.x;      // 4 edges per thread
    if (i >= EE / 4) return;
    int4 s = ((const int4*)ei)[i];
    int4 d = ((const int4*)(ei + EE))[i];
    float4 e0 = ((const float4*)ea)[i * 3 + 0];
    float4 e1 = ((const float4*)ea)[i * 3 + 1];
    float4 e2 = ((const float4*)ea)[i * 3 + 2];
    int p0 = atomicAdd(&cursor[d.x], 1);
    int p1 = atomicAdd(&cursor[d.y], 1);
    int p2 = atomicAdd(&cursor[d.z], 1);
    int p3 = atomicAdd(&cursor[d.w], 1);
    csr[p0] = make_float4(__int_as_float(s.x), e0.x, e0.y, e0.z);
    csr[p1] = make_float4(__int_as_float(s.y), e0.w, e1.x, e1.y);
    csr[p2] = make_float4(__int_as_float(s.z), e1.z, e1.w, e2.x);
    csr[p3] = make_float4(__int_as_float(s.w), e2.y, e2.z, e2.w);
}

// ---------------- W -> W^T split (bf16 hi/lo planes), once per weight ----------------
// W: [K][256] -> WTh/WTl [256][K] (caller offsets dst by 256*K for the second half)
__global__ __launch_bounds__(256) void cvt_wt(
    const float* __restrict__ W, unsigned short* __restrict__ WTh,
    unsigned short* __restrict__ WTl, int K)
{
    int i = blockIdx.x * 256 + threadIdx.x;
    if (i >= K * 256) return;
    int k = i >> 8, c = i & 255;
    float v = W[i];
    unsigned short h = f2b(v);
    unsigned short l = f2b(v - b2f(h));
    WTh[(size_t)c * K + k] = h;
    WTl[(size_t)c * K + k] = l;
}

// ---------------- fused split-bf16 MFMA GEMM: [xl|xr] = A @ [Wl|Wr] + bias ----------
// A fp32 [M x K] (split hi/lo on the fly); BT bf16 planes [512][K].
// Block: 256 thr (4 waves), tile 64x256; wave tile 32x128 = 2x8 MFMA 16x16 tiles.
// grid.x=2 selects column half: bn=0 -> (C0,bias0), bn=256 -> (C1,bias1).
__global__ __launch_bounds__(256) void gemm_fused(
    const float* __restrict__ A,
    const unsigned short* __restrict__ BTh, const unsigned short* __restrict__ BTl,
    const float* __restrict__ bias0, const float* __restrict__ bias1,
    float* __restrict__ C0, float* __restrict__ C1,
    int M, int K)
{
    __shared__ unsigned short Ah[64][36], Al[64][36];    // 72B row stride: 18-bank spread
    __shared__ unsigned short Bh[256][36], Bl[256][36];  // total LDS 46080 B
    const int tid = threadIdx.x;
    const int bm = blockIdx.y << 6;
    const int bn = blockIdx.x << 8;        // 0 or 256
    const int w  = tid >> 6, l = tid & 63;
    const int wr = w >> 1, wc = w & 1;
    const int lr = l & 15, lk = l >> 4;

    f32x4 acc[2][8];
#pragma unroll
    for (int a = 0; a < 2; a++)
#pragma unroll
        for (int b = 0; b < 8; b++) acc[a][b] = (f32x4){0.f, 0.f, 0.f, 0.f};

    const int ar = tid >> 2, ac = (tid & 3) << 3;   // A stage: row 0..63, k-chunk {0,8,16,24}

    for (int k0 = 0; k0 < K; k0 += 32) {
        // ---- stage A (fp32 -> bf16 hi/lo split in registers) ----
        float av[8];
        if (bm + ar < M) {
            *(float4*)&av[0] = *(const float4*)&A[(size_t)(bm + ar) * K + k0 + ac];
            *(float4*)&av[4] = *(const float4*)&A[(size_t)(bm + ar) * K + k0 + ac + 4];
        } else {
#pragma unroll
            for (int j = 0; j < 8; j++) av[j] = 0.f;
        }
        unsigned hp[4], lp[4];
#pragma unroll
        for (int j = 0; j < 4; j++) {
            unsigned short h0 = f2b(av[2 * j]),     h1 = f2b(av[2 * j + 1]);
            unsigned short l0 = f2b(av[2 * j]     - b2f(h0));
            unsigned short l1 = f2b(av[2 * j + 1] - b2f(h1));
            hp[j] = (unsigned)h0 | ((unsigned)h1 << 16);
            lp[j] = (unsigned)l0 | ((unsigned)l1 << 16);
        }
        *(uint4*)&Ah[ar][ac] = make_uint4(hp[0], hp[1], hp[2], hp[3]);
        *(uint4*)&Al[ar][ac] = make_uint4(lp[0], lp[1], lp[2], lp[3]);
        // ---- stage B (bf16 planes, pure copy): 256 rows x 64B, 4 reps ----
#pragma unroll
        for (int rep = 0; rep < 4; rep++) {
            int i  = (rep << 8) + tid;
            int rb = i >> 2, cb = (i & 3) << 3;
            *(uint4*)&Bh[rb][cb] = *(const uint4*)&BTh[(size_t)(bn + rb) * K + k0 + cb];
            *(uint4*)&Bl[rb][cb] = *(const uint4*)&BTl[(size_t)(bn + rb) * K + k0 + cb];
        }
        __syncthreads();

        bf16x8 afh[2], afl[2];
#pragma unroll
        for (int a = 0; a < 2; a++) {
            afh[a] = *(const bf16x8*)&Ah[wr * 32 + a * 16 + lr][lk << 3];
            afl[a] = *(const bf16x8*)&Al[wr * 32 + a * 16 + lr][lk << 3];
        }
#pragma unroll
        for (int b = 0; b < 8; b++) {
            bf16x8 bh = *(const bf16x8*)&Bh[wc * 128 + b * 16 + lr][lk << 3];
            bf16x8 bl_ = *(const bf16x8*)&Bl[wc * 128 + b * 16 + lr][lk << 3];
#pragma unroll
            for (int a = 0; a < 2; a++) {
                acc[a][b] = __builtin_amdgcn_mfma_f32_16x16x32_bf16(afh[a], bh,  acc[a][b], 0, 0, 0);
                acc[a][b] = __builtin_amdgcn_mfma_f32_16x16x32_bf16(afh[a], bl_, acc[a][b], 0, 0, 0);
                acc[a][b] = __builtin_amdgcn_mfma_f32_16x16x32_bf16(afl[a], bh,  acc[a][b], 0, 0, 0);
            }
        }
        __syncthreads();
    }

    // epilogue: D row=(lane>>4)*4+i, col=lane&15 within each 16x16 tile
    const float* bias = (bn == 0) ? bias0 : bias1;
    float* C = (bn == 0) ? C0 : C1;
#pragma unroll
    for (int a = 0; a < 2; a++) {
        int rbase = bm + wr * 32 + a * 16 + (lk << 2);
#pragma unroll
        for (int b = 0; b < 8; b++) {
            int c = wc * 128 + b * 16 + lr;        // 0..255 within half
            float bs = bias[c];
#pragma unroll
            for (int i = 0; i < 4; i++) {
                int rg = rbase + i;
                if (rg < M) C[(size_t)rg * HC + c] = acc[a][b][i] + bs;
            }
        }
    }
}

// ---------------- Fused per-node edge attention + aggregation ----------------
// One wave per 4 consecutive nodes (edge-weight constants hoisted across nodes).
// lane = h*16 + q; lane owns channels [4q..4q+3] of head h (flat offset lane*4).
__global__ __launch_bounds__(256) void gat_edge(
    const float* __restrict__ xl, const float* __restrict__ xr,
    const float4* __restrict__ csr, const int* __restrict__ row_start,
    const float* __restrict__ att, const float* __restrict__ We,
    const float* __restrict__ bias, float* __restrict__ out)
{
    const int lane = threadIdx.x & 63;
    const int wid  = (blockIdx.x * 256 + threadIdx.x) >> 6;   // 0..12499
    const int base = wid << 2;                                 // 4 nodes per wave
    const int j4 = lane << 2;
    const float4* xlv = (const float4*)xl;     // node row = 64 float4s

    const float4 at4 = *(const float4*)&att[j4];
    const float4 w0  = *(const float4*)&We[j4];
    const float4 w1  = *(const float4*)&We[HC + j4];
    const float4 w2  = *(const float4*)&We[2 * HC + j4];

#pragma unroll 1
    for (int v = 0; v < 4; v++) {
        const int node = base + v;                             // < 50000 always
        const float4 xr4 = *(const float4*)&xr[(size_t)node * HC + j4];

        float acc0 = 0.f, acc1 = 0.f, acc2 = 0.f, acc3 = 0.f, denom = 0.f;
        float eas0 = 0.f, eas1 = 0.f, eas2 = 0.f;
        const int beg = row_start[node];
        const int n   = row_start[node + 1] - beg;
        const float4* cp = csr + beg;

        float4 r0 = {0,0,0,0}, r1 = {0,0,0,0}, r2 = {0,0,0,0};
        float4 v0 = {0,0,0,0}, v1 = {0,0,0,0};
        if (n > 0) { r0 = cp[0]; v0 = xlv[(size_t)__float_as_int(r0.x) * 64 + lane]; }
        if (n > 1) { r1 = cp[1]; v1 = xlv[(size_t)__float_as_int(r1.x) * 64 + lane]; }
        if (n > 2) { r2 = cp[2]; }

        for (int i = 0; i < n; i++) {
            float4 crec = r0, cxv = v0;
            r0 = r1; r1 = r2; v0 = v1;
            if (i + 3 < n) r2 = cp[i + 3];
            if (i + 2 < n) v1 = xlv[(size_t)__float_as_int(r1.x) * 64 + lane];

            float ea0 = crec.y, ea1 = crec.z, ea2 = crec.w;
            eas0 += ea0; eas1 += ea1; eas2 += ea2;
            float m0 = cxv.x + xr4.x + ea0 * w0.x + ea1 * w1.x + ea2 * w2.x;
            float m1 = cxv.y + xr4.y + ea0 * w0.y + ea1 * w1.y + ea2 * w2.y;
            float m2 = cxv.z + xr4.z + ea0 * w0.z + ea1 * w1.z + ea2 * w2.z;
            float m3 = cxv.w + xr4.w + ea0 * w0.w + ea1 * w1.w + ea2 * w2.w;
            m0 = fmaxf(m0, NSLOPE * m0);           // leaky-relu as single v_max
            m1 = fmaxf(m1, NSLOPE * m1);
            m2 = fmaxf(m2, NSLOPE * m2);
            m3 = fmaxf(m3, NSLOPE * m3);
            float p = m0 * at4.x + m1 * at4.y + m2 * at4.z + m3 * at4.w;
            p += __shfl_xor(p, 1);
            p += __shfl_xor(p, 2);
            p += __shfl_xor(p, 4);
            p += __shfl_xor(p, 8);
            // softmax shift-invariant; alpha O(1) so no max subtraction needed
            float ex = __expf(p);
            denom += ex;
            acc0 = fmaf(ex, cxv.x, acc0);
            acc1 = fmaf(ex, cxv.y, acc1);
            acc2 = fmaf(ex, cxv.z, acc2);
            acc3 = fmaf(ex, cxv.w, acc3);
        }

        {   // self loop: attr = mean of incoming edge attrs (0 if none)
            float rd = 1.0f / fmaxf((float)n, 1.0f);
            float ea0 = eas0 * rd, ea1 = eas1 * rd, ea2 = eas2 * rd;
            float4 sv = xlv[(size_t)node * 64 + lane];
            float m0 = sv.x + xr4.x + ea0 * w0.x + ea1 * w1.x + ea2 * w2.x;
            float m1 = sv.y + xr4.y + ea0 * w0.y + ea1 * w1.y + ea2 * w2.y;
            float m2 = sv.z + xr4.z + ea0 * w0.z + ea1 * w1.z + ea2 * w2.z;
            float m3 = sv.w + xr4.w + ea0 * w0.w + ea1 * w1.w + ea2 * w2.w;
            m0 = fmaxf(m0, NSLOPE * m0);
            m1 = fmaxf(m1, NSLOPE * m1);
            m2 = fmaxf(m2, NSLOPE * m2);
            m3 = fmaxf(m3, NSLOPE * m3);
            float p = m0 * at4.x + m1 * at4.y + m2 * at4.z + m3 * at4.w;
            p += __shfl_xor(p, 1);
            p += __shfl_xor(p, 2);
            p += __shfl_xor(p, 4);
            p += __shfl_xor(p, 8);
            float ex = __expf(p);
            denom += ex;
            acc0 = fmaf(ex, sv.x, acc0);
            acc1 = fmaf(ex, sv.y, acc1);
            acc2 = fmaf(ex, sv.z, acc2);
            acc3 = fmaf(ex, sv.w, acc3);
        }

        const float inv = 1.0f / denom;
        float r0s = acc0 * inv, r1s = acc1 * inv, r2s = acc2 * inv, r3s = acc3 * inv;
        // head mean: lanes l, l+16, l+32, l+48 hold heads 0..3 of the same channels
        r0s += __shfl_xor(r0s, 16); r0s += __shfl_xor(r0s, 32);
        r1s += __shfl_xor(r1s, 16); r1s += __shfl_xor(r1s, 32);
        r2s += __shfl_xor(r2s, 16); r2s += __shfl_xor(r2s, 32);
        r3s += __shfl_xor(r3s, 16); r3s += __shfl_xor(r3s, 32);
        if (lane < 16) {
            float4 bv = *(const float4*)&bias[j4];
            float4 o;
            o.x = fmaxf(0.25f * r0s + bv.x, 0.f);   // mean over H=4 heads, +bias, ReLU
            o.y = fmaxf(0.25f * r1s + bv.y, 0.f);
            o.z = fmaxf(0.25f * r2s + bv.z, 0.f);
            o.w = fmaxf(0.25f * r3s + bv.w, 0.f);
            *(float4*)&out[(size_t)node * 64 + j4] = o;
        }
    }
}

// ---------------- final linear: out[N x 32] = h[N x 64] @ Wmu + bmu ----------------
__global__ __launch_bounds__(256) void mu_kernel(
    const float* __restrict__ h, const float* __restrict__ Wmu,
    const float* __restrict__ bmu, float* __restrict__ out)
{
    __shared__ float ws[64 * 32];
    __shared__ float hs[8 * 64];
    const int tid = threadIdx.x;
#pragma unroll
    for (int i = 0; i < 8; i++) ws[tid + i * 256] = Wmu[tid + i * 256];
    const int nb = blockIdx.x * 8;   // 8 nodes/block, NN % 8 == 0
    {
        int idx = tid * 2;
        *(float2*)&hs[idx] = *(const float2*)&h[(size_t)nb * 64 + idx];
    }
    __syncthreads();
    const int ln = tid >> 5;     // 0..7
    const int o  = tid & 31;
    float acc = bmu[o];
#pragma unroll
    for (int k = 0; k < 64; k++) acc = fmaf(hs[ln * 64 + k], ws[k * 32 + o], acc);
    out[(size_t)(nb + ln) * 32 + o] = acc;
}

// ---------------- launch ----------------
extern "C" void kernel_launch(void* const* d_in, const int* in_sizes, int n_in,
                              void* d_out, int out_size, void* d_ws, size_t ws_size,
                              hipStream_t stream) {
    const float* x    = (const float*)d_in[0];
    const int*   ei   = (const int*)  d_in[1];
    const float* ea   = (const float*)d_in[2];
    const float* Wl0  = (const float*)d_in[3];
    const float* bl0  = (const float*)d_in[4];
    const float* Wr0  = (const float*)d_in[5];
    const float* br0  = (const float*)d_in[6];
    const float* We0  = (const float*)d_in[7];
    const float* att0 = (const float*)d_in[8];
    const float* bi0  = (const float*)d_in[9];
    const float* Wl1  = (const float*)d_in[10];
    const float* bl1  = (const float*)d_in[11];
    const float* Wr1  = (const float*)d_in[12];
    const float* br1  = (const float*)d_in[13];
    const float* We1  = (const float*)d_in[14];
    const float* att1 = (const float*)d_in[15];
    const float* bi1  = (const float*)d_in[16];
    const float* Wmu  = (const float*)d_in[17];
    const float* bmu  = (const float*)d_in[18];
    float* out = (float*)d_out;

    // workspace carve-up (~129.2 MB, same footprint class as proven R1-R3)
    float* xl32 = (float*)d_ws;                        // NN*256
    float* xr32 = xl32 + (size_t)NN * HC;              // NN*256
    float* h1   = xr32 + (size_t)NN * HC;              // NN*64
    int*   deg  = (int*)(h1 + (size_t)NN * 64);        // NN
    int*   rows = deg + NN;                            // NN+1
    int*   curs = rows + NN + 1;                       // NN
    uintptr_t p = (uintptr_t)(curs + NN);
    p = (p + 15) & ~(uintptr_t)15;
    unsigned short* WT0h = (unsigned short*)p;         // [512][256]
    unsigned short* WT0l = WT0h + 512 * 256;
    unsigned short* WT1h = WT0l + 512 * 256;           // [512][64]
    unsigned short* WT1l = WT1h + 512 * 64;
    p = (uintptr_t)(WT1l + 512 * 64);
    p = (p + 255) & ~(uintptr_t)255;
    float4* csr = (float4*)p;                          // EE records

    // CSR build (shared by both layers)
    hipMemsetAsync(deg, 0, NN * sizeof(int), stream);
    deg_kernel<<<(EE / 4 + 255) / 256, 256, 0, stream>>>(ei + EE, deg);
    scan_kernel<<<1, 1024, 0, stream>>>(deg, rows, curs);
    scatter_kernel<<<(EE / 4 + 255) / 256, 256, 0, stream>>>(ei, ea, curs, csr);

    // weight transpose+split into fused [512][K] planes (tiny, once)
    cvt_wt<<<256, 256, 0, stream>>>(Wl0, WT0h,             WT0l,             256);
    cvt_wt<<<256, 256, 0, stream>>>(Wr0, WT0h + 256 * 256, WT0l + 256 * 256, 256);
    cvt_wt<<< 64, 256, 0, stream>>>(Wl1, WT1h,             WT1l,             64);
    cvt_wt<<< 64, 256, 0, stream>>>(Wr1, WT1h + 256 * 64,  WT1l + 256 * 64,  64);

    dim3 gg(2, (NN + 63) / 64);
    const int gat_grid = NN / 16;           // 4 waves/block x 4 nodes/wave

    // layer 0
    gemm_fused<<<gg, 256, 0, stream>>>(x, WT0h, WT0l, bl0, br0, xl32, xr32, NN, 256);
    gat_edge<<<gat_grid, 256, 0, stream>>>(xl32, xr32, csr, rows, att0, We0, bi0, h1);

    // layer 1
    gemm_fused<<<gg, 256, 0, stream>>>(h1, WT1h, WT1l, bl1, br1, xl32, xr32, NN, 64);
    gat_edge<<<gat_grid, 256, 0, stream>>>(xl32, xr32, csr, rows, att1, We1, bi1, h1);

    // head
    mu_kernel<<<NN / 8, 256, 0, stream>>>(h1, Wmu, bmu, out);
}